// Round 15
// baseline (259.670 us; speedup 1.0000x reference)
//
#include <hip/hip_runtime.h>
#include <hip/hip_bf16.h>

#define N_NODES 50000
#define N_EDGES 800000
#define NPAD    50048   // 391*128
#define SCAN_B  196     // ceil(50000/256)
#define HIST_B  3125    // 800000/256
#define PW1_B   1536    // 1024*384/256
#define PW2_B   32      // 32*256/256
#define GEMM_B  (((NPAD / 128 + 7) / 8) * 32)   // 1568
#define SCAT_B  ((N_EDGES + 511) / 512)         // 1563

typedef __attribute__((ext_vector_type(8))) short bf16x8;
typedef __attribute__((ext_vector_type(8))) unsigned short u16x8;
typedef __attribute__((ext_vector_type(4))) float f32x4;

__device__ __forceinline__ unsigned short f2bf(float f) {
  union { float f; unsigned u; } x; x.f = f;
  unsigned r = x.u + 0x7fffu + ((x.u >> 16) & 1u);
  return (unsigned short)(r >> 16);
}
__device__ __forceinline__ float bf2f(unsigned short u) {
  union { unsigned u; float f; } x; x.u = ((unsigned)u) << 16;
  return x.f;
}
// pack two floats -> 2xbf16 word (RNE; compiler emits v_cvt_pk_bf16_f32)
__device__ __forceinline__ unsigned pkbf(float lo, float hi) {
  return ((unsigned)f2bf(hi) << 16) | f2bf(lo);
}
// v: biased u8, scale 16: b = clamp(round(v*16)+128, 0,255); v = (b-128)/16
__device__ __forceinline__ unsigned char enc8v(float v) {
  float t = fminf(fmaxf(fmaf(v, 16.f, 128.5f), 0.f), 255.f);
  return (unsigned char)(int)t;
}
// k: signed i8, scale 16
__device__ __forceinline__ char enc8k(float v) {
  float t = fminf(fmaxf(v * 16.f, -127.f), 127.f);
  return (char)(int)floorf(t + 0.5f);
}
// q: signed i8, scale 24 (clip at |q|>5.29 -- ~1 element in 12.8M)
__device__ __forceinline__ char enc8q(float v) {
  float t = fminf(fmaxf(v * 24.f, -127.f), 127.f);
  return (char)(int)floorf(t + 0.5f);
}

__device__ __forceinline__ int dot4i8(int a, int b, int c) {
#if __has_builtin(__builtin_amdgcn_sdot4)
  return __builtin_amdgcn_sdot4(a, b, c, false);
#else
  int r = c;
  r += (int)(char)(a) * (int)(char)(b);
  r += (int)(char)(a >> 8) * (int)(char)(b >> 8);
  r += (int)(char)(a >> 16) * (int)(char)(b >> 16);
  r += (int)(char)(a >> 24) * (int)(char)(b >> 24);
  return r;
#endif
}

// async global->LDS, 16B per lane (dest must be linear: base + lane*16)
__device__ __forceinline__ void gload16(const void* g, void* l) {
  __builtin_amdgcn_global_load_lds(
      (const __attribute__((address_space(1))) unsigned int*)g,
      (__attribute__((address_space(3))) unsigned int*)l, 16, 0, 0);
}

// ---------------- fused CSR scan (replaces scan1+scan2+scan3) ----------------
// 196 blocks, all co-resident (<=256 CUs). Each block: local Hillis-Steele scan,
// publish block total, device-scope barrier via atomic counter, then sum
// predecessor totals (coherent atomic reads) and write offsets/cursor.
__global__ __launch_bounds__(256) void scan_kernel(const int* __restrict__ counts,
                                                   int* __restrict__ offsets,
                                                   int* __restrict__ cursor,
                                                   int* __restrict__ bsum,
                                                   int* __restrict__ done,
                                                   int n, int E) {
  __shared__ int sm[256];
  int i = blockIdx.x * 256 + threadIdx.x;
  int v = (i < n) ? counts[i] : 0;
  sm[threadIdx.x] = v;
  __syncthreads();
  for (int off = 1; off < 256; off <<= 1) {
    int t = (threadIdx.x >= off) ? sm[threadIdx.x - off] : 0;
    __syncthreads();
    sm[threadIdx.x] += t;
    __syncthreads();
  }
  int local_ex = sm[threadIdx.x] - v;
  if (threadIdx.x == 255) {
    bsum[blockIdx.x] = sm[255];
    __threadfence();                 // publish bsum device-wide
    atomicAdd(done, 1);
  }
  if (threadIdx.x == 0) {
    while (atomicAdd(done, 0) < (int)gridDim.x) { }   // all blocks published
  }
  __syncthreads();                   // also: everyone done reading sm
  int base = 0;
  for (int jj = threadIdx.x; jj < (int)blockIdx.x; jj += 256)
    base += atomicAdd(&bsum[jj], 0); // coherent read
  sm[threadIdx.x] = base;
  __syncthreads();
  for (int off = 128; off > 0; off >>= 1) {
    if (threadIdx.x < off) sm[threadIdx.x] += sm[threadIdx.x + off];
    __syncthreads();
  }
  base = sm[0];
  if (i < n) {
    int o = base + local_ex;
    offsets[i] = o;
    cursor[i] = o;
  }
  if (i == 0) offsets[n] = E;
}

// ---------------- fused prep: hist + pack_w1 + pack_w2 ----------------
__global__ __launch_bounds__(256) void prep_kernel(
    const int* __restrict__ edst, int* __restrict__ counts,
    const float* __restrict__ Wq1, const float* __restrict__ Wk1,
    const float* __restrict__ Wv1, const float* __restrict__ Ws1,
    const float* __restrict__ bq1, const float* __restrict__ bk1,
    const float* __restrict__ bv1, const float* __restrict__ bs1,
    unsigned short* __restrict__ wbt, float* __restrict__ bias1,
    const float* __restrict__ Wq2, const float* __restrict__ Wk2,
    const float* __restrict__ Wv2, const float* __restrict__ Ws2,
    const float* __restrict__ bq2, const float* __restrict__ bk2,
    const float* __restrict__ bv2, const float* __restrict__ bs2,
    unsigned short* __restrict__ w2bt, float* __restrict__ bias2) {
  int b = blockIdx.x;
  if (b < HIST_B) {
    int e = b * 256 + threadIdx.x;
    if (e < N_EDGES) atomicAdd(&counts[edst[e]], 1);
  } else if (b < HIST_B + PW1_B) {
    int idx = (b - HIST_B) * 256 + threadIdx.x;
    int n = idx / 384, k = idx - n * 384;
    int blk = n >> 8, cc = n & 255;
    const float* W = (blk == 0) ? Wq1 : (blk == 1) ? Wk1 : (blk == 2) ? Wv1 : Ws1;
    wbt[idx] = f2bf(W[(long)k * 256 + cc]);   // wbt[n][k] = W[k][cc] (transposed)
    if (k == 0) {
      const float* bb = (blk == 0) ? bq1 : (blk == 1) ? bk1 : (blk == 2) ? bv1 : bs1;
      bias1[n] = bb[cc];
    }
  } else {
    int idx = (b - HIST_B - PW1_B) * 256 + threadIdx.x;
    int c = idx >> 8, p = idx & 255;
    unsigned short o = 0;
    if (c < 20) {
      int blk = c / 5, cc = c - blk * 5;
      int tch = (p & 0xC0) + (p & 3) * 16 + ((p & 63) >> 2);   // inverse permutation
      const float* W = (blk == 0) ? Wq2 : (blk == 1) ? Wk2 : (blk == 2) ? Wv2 : Ws2;
      o = f2bf(W[(long)tch * 5 + cc]);
      if (p == 0) {
        const float* bb = (blk == 0) ? bq2 : (blk == 1) ? bk2 : (blk == 2) ? bv2 : bs2;
        bias2[c] = bb[cc];
      }
    }
    w2bt[idx] = o;
  }
}

// ---------------- layer-1 fused QKVS GEMM (dbuf B) + edge scatter ----------------
// bid < GEMM_B: GEMM. BK=64, A reg-staged fp32 (post-barrier prefetch, R11),
// B DOUBLE-BUFFERED LDS: gloads for kt+1 issued AFTER barrier2 into Bs[b^1],
// drained at the NEXT iteration's barrier1 (after the full MFMA phase) ->
// no exposed B round-trip; barrier2 drains lgkm only. LDS 16+64 = 80 KB.
// bid >= GEMM_B: CSR edge scatter (overlaps under the GEMM).
// y=0 q i8(24); y=1 k i8(16); y=2 v u8-biased; y=3 skip bf16; permuted channels.
// 1D grid XCD-grouped: 4 y-blocks of one m-panel share bid%8 -> same XCD L2.
__global__ __launch_bounds__(512) void gemm_scatter_kernel(
    const float* __restrict__ x, const unsigned short* __restrict__ wbt,
    const float* __restrict__ bias,
    char* __restrict__ qb8, unsigned char* __restrict__ kvb,
    unsigned short* __restrict__ s1b,
    const int* __restrict__ esrc, const int* __restrict__ edst,
    int* __restrict__ cursor, int* __restrict__ csr_src) {
  __shared__ unsigned short As[128 * 64];       // 16 KB
  __shared__ unsigned short Bs[2 * 256 * 64];   // 64 KB (double buffer)
  int bid = blockIdx.x;
  if (bid >= GEMM_B) {                      // ---- scatter tail ----
    int e = (bid - GEMM_B) * 512 + threadIdx.x;
    if (e < N_EDGES) {
      int pos = atomicAdd(&cursor[edst[e]], 1);
      csr_src[pos] = esrc[e];
    }
    return;
  }
  int grp = bid >> 5, bl = bid & 31;
  int mx = grp * 8 + (bl & 7);
  int y = bl >> 3;
  if (mx >= NPAD / 128) return;   // uniform per block
  int tid = threadIdx.x;
  long m0 = (long)mx * 128;
  int n0 = y * 256;
  int w = tid >> 6, l = tid & 63;
  int wr = (w >> 2) * 64, wc = (w & 3) * 64;
  int lr = l & 15, c0 = l >> 4;
  int lj = lr & 7;                          // (fragment row)&7, all mf/nf alike
  f32x4 acc[4][4] = {};
  // A staging: thread -> rows ra and ra+64, LDS chunk cs=tid&7,
  // source chunk cg = cs ^ (ra&7)  ((ra+64)&7 == ra&7).
  int ra = tid >> 3, cs = tid & 7;
  int cg = cs ^ (ra & 7);
  long ar0 = m0 + ra;      if (ar0 > (long)(N_NODES - 1)) ar0 = N_NODES - 1;
  long ar1 = m0 + 64 + ra; if (ar1 > (long)(N_NODES - 1)) ar1 = N_NODES - 1;
  const float* gA0 = x + ar0 * 384 + cg * 8;
  const float* gA1 = x + ar1 * 384 + cg * 8;
  unsigned short* aw0 = &As[ra * 64 + cs * 8];
  unsigned short* aw1 = &As[(ra + 64) * 64 + cs * 8];
  // B staging: 4 gload16/thread; row (tid>>3)+r*64, LDS chunk cs,
  // source chunk = cs ^ (row&7) (row&7 == ra&7 for all r).
  const unsigned short* gB[4];
#pragma unroll
  for (int r = 0; r < 4; ++r)
    gB[r] = wbt + (long)(n0 + ra + r * 64) * 384 + cg * 8;
  // prologue: A regs + B buf0 for kt=0
  float4 a00 = *(const float4*)gA0, a01 = *(const float4*)(gA0 + 4);
  float4 a10 = *(const float4*)gA1, a11 = *(const float4*)(gA1 + 4);
#pragma unroll
  for (int r = 0; r < 4; ++r)
    gload16(gB[r], &Bs[(tid + r * 512) * 8]);
  for (int kt = 0; kt < 6; ++kt) {
    int b = kt & 1;
    __syncthreads();   // barrier1: drains B gloads for kt (issued last iter,
                       // hidden under kt-1's MFMA) + A reg loads; As readers done
    {
      union { bf16x8 v; unsigned u[4]; } t;
      t.u[0] = pkbf(a00.x, a00.y); t.u[1] = pkbf(a00.z, a00.w);
      t.u[2] = pkbf(a01.x, a01.y); t.u[3] = pkbf(a01.z, a01.w);
      *(bf16x8*)aw0 = t.v;
      t.u[0] = pkbf(a10.x, a10.y); t.u[1] = pkbf(a10.z, a10.w);
      t.u[2] = pkbf(a11.x, a11.y); t.u[3] = pkbf(a11.z, a11.w);
      *(bf16x8*)aw1 = t.v;
    }
    __syncthreads();   // barrier2: lgkm only (A writes visible); no vmem pending
    if (kt < 5) {      // prefetch kt+1 AFTER barrier2 -> drains next barrier1
      int ko2 = (kt + 1) * 64;
#pragma unroll
      for (int r = 0; r < 4; ++r)
        gload16(gB[r] + ko2, &Bs[(b ^ 1) * 16384 + (tid + r * 512) * 8]);
      a00 = *(const float4*)(gA0 + ko2); a01 = *(const float4*)(gA0 + ko2 + 4);
      a10 = *(const float4*)(gA1 + ko2); a11 = *(const float4*)(gA1 + ko2 + 4);
    }
    const unsigned short* Bb = &Bs[b * 16384];
#pragma unroll
    for (int ks = 0; ks < 2; ++ks) {
      int pc = ((ks * 4 + c0) ^ lj) * 8;   // physical chunk offset (elements)
      bf16x8 af[4], bfv[4];
#pragma unroll
      for (int mf = 0; mf < 4; ++mf)
        af[mf] = *(const bf16x8*)&As[(wr + mf * 16 + lr) * 64 + pc];
#pragma unroll
      for (int nf = 0; nf < 4; ++nf)
        bfv[nf] = *(const bf16x8*)&Bb[(wc + nf * 16 + lr) * 64 + pc];
#pragma unroll
      for (int mf = 0; mf < 4; ++mf)
#pragma unroll
        for (int nf = 0; nf < 4; ++nf)
          acc[mf][nf] = __builtin_amdgcn_mfma_f32_16x16x32_bf16(af[mf], bfv[nf], acc[mf][nf], 0, 0, 0);
    }
  }
  float bv[4];
#pragma unroll
  for (int nf = 0; nf < 4; ++nf) bv[nf] = bias[n0 + wc + nf * 16 + lr];
  int pos = wc + lr * 4;
#pragma unroll
  for (int mf = 0; mf < 4; ++mf) {
#pragma unroll
    for (int i = 0; i < 4; ++i) {
      long row = m0 + wr + mf * 16 + c0 * 4 + i;
      float v0 = acc[mf][0][i] + bv[0];
      float v1 = acc[mf][1][i] + bv[1];
      float v2 = acc[mf][2][i] + bv[2];
      float v3 = acc[mf][3][i] + bv[3];
      if (y == 0) {
        char4 st; st.x = enc8q(v0); st.y = enc8q(v1); st.z = enc8q(v2); st.w = enc8q(v3);
        *(char4*)&qb8[row * 256 + pos] = st;
      } else if (y == 1) {
        char4 st; st.x = enc8k(v0); st.y = enc8k(v1); st.z = enc8k(v2); st.w = enc8k(v3);
        *(char4*)&kvb[row * 512 + pos] = st;
      } else if (y == 2) {
        uchar4 st; st.x = enc8v(v0); st.y = enc8v(v1); st.z = enc8v(v2); st.w = enc8v(v3);
        *(uchar4*)&kvb[row * 512 + 256 + pos] = st;
      } else {
        ushort4 st; st.x = f2bf(v0); st.y = f2bf(v1); st.z = f2bf(v2); st.w = f2bf(v3);
        *(ushort4*)&s1b[row * 256 + pos] = st;
      }
    }
  }
}

// ---------------- layer-1 fused attention aggregation (i8 kv, sdot4, pipelined) ----------------
__global__ __launch_bounds__(256) void agg1_kernel(
    const char* __restrict__ qb8, const unsigned char* __restrict__ kvb,
    unsigned short* s1b,
    const int* __restrict__ offsets, const int* __restrict__ csr_src) {
  int w = threadIdx.x >> 6, l = threadIdx.x & 63;
  int g = l >> 4;            // edge slot 0..3
  int sub = l & 15;          // channel block (head = sub>>2)
  for (int n = blockIdx.x * 4 + w; n < N_NODES; n += gridDim.x * 4) {
    int i0 = offsets[n], i1 = offsets[n + 1];
    long ob = (long)n * 256 + sub * 16;
    if (i0 >= i1) {          // deg-0: h = relu(skip)
      if (g == 0) {
        u16x8 sv0 = *(const u16x8*)&s1b[ob];
        u16x8 sv1 = *(const u16x8*)&s1b[ob + 8];
        u16x8 h0, h1;
#pragma unroll
        for (int j = 0; j < 8; ++j) {
          h0[j] = (short)f2bf(fmaxf(bf2f((unsigned short)sv0[j]), 0.f));
          h1[j] = (short)f2bf(fmaxf(bf2f((unsigned short)sv1[j]), 0.f));
        }
        *(u16x8*)&s1b[ob] = h0;
        *(u16x8*)&s1b[ob + 8] = h1;
      }
      continue;
    }
    int4 qi = *(const int4*)&qb8[(long)n * 256 + sub * 16];
    float acc[16] = {};
    float se = 0.f;

    auto ldbatch = [&](int i, int4& ka, uint4& va, int4& kw, uint4& vw) {
      int ia = i + g, ib = i + 4 + g;
      int sa = csr_src[ia < i1 ? ia : i1 - 1];
      int sb = csr_src[ib < i1 ? ib : i1 - 1];
      const char* ba = (const char*)kvb + (long)sa * 512 + sub * 16;
      const char* bb = (const char*)kvb + (long)sb * 512 + sub * 16;
      ka = *(const int4*)ba; va = *(const uint4*)(ba + 256);
      kw = *(const int4*)bb; vw = *(const uint4*)(bb + 256);
    };
#define VACC(E, W, B) \
    acc[(B) + 0] = fmaf(E, (float)((W) & 0xffu), acc[(B) + 0]); \
    acc[(B) + 1] = fmaf(E, (float)(((W) >> 8) & 0xffu), acc[(B) + 1]); \
    acc[(B) + 2] = fmaf(E, (float)(((W) >> 16) & 0xffu), acc[(B) + 2]); \
    acc[(B) + 3] = fmaf(E, (float)((W) >> 24), acc[(B) + 3]);
    auto consume = [&](int i, int4 ka, uint4 va, int4 kw, uint4 vw) {
      int ia = i + g, ib = i + 4 + g;
      int da = 0, db = 0;
      da = dot4i8(qi.x, ka.x, da); da = dot4i8(qi.y, ka.y, da);
      da = dot4i8(qi.z, ka.z, da); da = dot4i8(qi.w, ka.w, da);
      db = dot4i8(qi.x, kw.x, db); db = dot4i8(qi.y, kw.y, db);
      db = dot4i8(qi.z, kw.z, db); db = dot4i8(qi.w, kw.w, db);
      da += __shfl_xor(da, 1); da += __shfl_xor(da, 2);
      db += __shfl_xor(db, 1); db += __shfl_xor(db, 2);
      float ea = (ia < i1) ? __expf((float)da * (1.f / 3072.f)) : 0.f;
      float eb = (ib < i1) ? __expf((float)db * (1.f / 3072.f)) : 0.f;
      se += ea + eb;
      VACC(ea, va.x, 0) VACC(ea, va.y, 4) VACC(ea, va.z, 8) VACC(ea, va.w, 12)
      VACC(eb, vw.x, 0) VACC(eb, vw.y, 4) VACC(eb, vw.z, 8) VACC(eb, vw.w, 12)
    };

    int i = i0;
    int4 ka0, kw0; uint4 va0, vw0;
    ldbatch(i, ka0, va0, kw0, vw0);
    for (; i + 8 < i1; i += 8) {
      int4 ka1, kw1; uint4 va1, vw1;
      ldbatch(i + 8, ka1, va1, kw1, vw1);     // prefetch next batch
      consume(i, ka0, va0, kw0, vw0);
      ka0 = ka1; va0 = va1; kw0 = kw1; vw0 = vw1;
    }
    consume(i, ka0, va0, kw0, vw0);
#undef VACC
#pragma unroll
    for (int j = 0; j < 16; ++j) {
      acc[j] += __shfl_xor(acc[j], 16);
      acc[j] += __shfl_xor(acc[j], 32);
    }
    se += __shfl_xor(se, 16);
    se += __shfl_xor(se, 32);
    if (g == 0) {
      float inv = (se > 0.f) ? 1.0f / se : 0.f;
      float bias = (se > 0.f) ? -8.0f : 0.f;
      u16x8 sv0 = *(const u16x8*)&s1b[ob];
      u16x8 sv1 = *(const u16x8*)&s1b[ob + 8];
      u16x8 h0, h1;
#pragma unroll
      for (int j = 0; j < 8; ++j) {
        float v0 = fmaf(acc[j] * inv, 0.0625f, bias);
        float v1 = fmaf(acc[8 + j] * inv, 0.0625f, bias);
        h0[j] = (short)f2bf(fmaxf(v0 + bf2f((unsigned short)sv0[j]), 0.f));
        h1[j] = (short)f2bf(fmaxf(v1 + bf2f((unsigned short)sv1[j]), 0.f));
      }
      *(u16x8*)&s1b[ob] = h0;
      *(u16x8*)&s1b[ob + 8] = h1;
    }
  }
}

// ---------------- layer-2 linear via MFMA: [NPAD x 256] @ [256 x 32] ----------------
__global__ __launch_bounds__(256) void lin2_kernel(const unsigned short* __restrict__ hb,
                                                   const unsigned short* __restrict__ w2bt,
                                                   const float* __restrict__ bias2,
                                                   float* __restrict__ qs2, float* __restrict__ kv2) {
  __shared__ unsigned short Bs2[32 * 264];
  __shared__ float bsh[32];
  for (int i = threadIdx.x; i < 32 * 32; i += 256) {
    int r = i >> 5, cc = i & 31;
    *(u16x8*)&Bs2[r * 264 + cc * 8] = *(const u16x8*)&w2bt[r * 256 + cc * 8];
  }
  if (threadIdx.x < 32) bsh[threadIdx.x] = (threadIdx.x < 20) ? bias2[threadIdx.x] : 0.f;
  __syncthreads();
  int w = threadIdx.x >> 6, l = threadIdx.x & 63;
  long row0 = (long)blockIdx.x * 128 + w * 32;
  int lr = l & 15, c0 = l >> 4;
  f32x4 acc[2][2] = {};
  for (int kk = 0; kk < 8; ++kk) {
    int koff = kk * 32 + c0 * 8;
    bf16x8 af[2], bfv[2];
    af[0] = *(const bf16x8*)&hb[(row0 + lr) * 256 + koff];
    af[1] = *(const bf16x8*)&hb[(row0 + 16 + lr) * 256 + koff];
    bfv[0] = *(const bf16x8*)&Bs2[lr * 264 + koff];
    bfv[1] = *(const bf16x8*)&Bs2[(16 + lr) * 264 + koff];
#pragma unroll
    for (int mf = 0; mf < 2; ++mf)
#pragma unroll
      for (int nf = 0; nf < 2; ++nf)
        acc[mf][nf] = __builtin_amdgcn_mfma_f32_16x16x32_bf16(af[mf], bfv[nf], acc[mf][nf], 0, 0, 0);
  }
#pragma unroll
  for (int mf = 0; mf < 2; ++mf) {
#pragma unroll
    for (int nf = 0; nf < 2; ++nf) {
      int col = nf * 16 + lr;
#pragma unroll
      for (int i = 0; i < 4; ++i) {
        long n = row0 + mf * 16 + c0 * 4 + i;
        float v = acc[mf][nf][i] + bsh[col];
        if (col < 5) qs2[n * 12 + col] = v;
        else if (col < 15) kv2[n * 12 + (col - 5)] = v;
        else if (col < 20) qs2[n * 12 + (col - 10)] = v;
      }
    }
  }
}

// ---------------- layer-2 fused attention (1 thread per node) ----------------
__global__ void agg2_kernel(const float* __restrict__ qs2, const float* __restrict__ kv2,
                            const int* __restrict__ offsets, const int* __restrict__ csr_src,
                            float* __restrict__ out) {
  int n = blockIdx.x * 256 + threadIdx.x;
  if (n >= N_NODES) return;
  const float* bn = &qs2[(long)n * 12];
  const float is5 = 0.4472135954999579f;  // 1/sqrt(5)
  float q[5], acc[5] = {0, 0, 0, 0, 0}, se = 0.f;
#pragma unroll
  for (int c = 0; c < 5; ++c) q[c] = bn[c] * is5;
  int i0 = offsets[n], i1 = offsets[n + 1];
  for (int i = i0; i < i1; ++i) {
    int s = csr_src[i];
    const float4* ps = (const float4*)&kv2[(long)s * 12];
    float4 A = ps[0], B = ps[1], C = ps[2];
    float lg = q[0] * A.x + q[1] * A.y + q[2] * A.z + q[3] * A.w + q[4] * B.x;
    float ee = __expf(lg);
    se += ee;
    acc[0] += ee * B.y; acc[1] += ee * B.z; acc[2] += ee * B.w;
    acc[3] += ee * C.x; acc[4] += ee * C.y;
  }
  float inv = 1.f / (se + 1e-16f);
#pragma unroll
  for (int c = 0; c < 5; ++c) out[(long)n * 5 + c] = acc[c] * inv + bn[5 + c];
}

// ---------------- launch ----------------
extern "C" void kernel_launch(void* const* d_in, const int* in_sizes, int n_in,
                              void* d_out, int out_size, void* d_ws, size_t ws_size,
                              hipStream_t stream) {
  (void)in_sizes; (void)n_in; (void)out_size; (void)ws_size;
  const float* x   = (const float*)d_in[0];
  const int* eidx  = (const int*)d_in[1];
  const int* esrc  = eidx;
  const int* edst  = eidx + N_EDGES;
  const float* Wq1 = (const float*)d_in[2];  const float* bq1 = (const float*)d_in[3];
  const float* Wk1 = (const float*)d_in[4];  const float* bk1 = (const float*)d_in[5];
  const float* Wv1 = (const float*)d_in[6];  const float* bv1 = (const float*)d_in[7];
  const float* Ws1 = (const float*)d_in[8];  const float* bs1 = (const float*)d_in[9];
  const float* Wq2 = (const float*)d_in[10]; const float* bq2 = (const float*)d_in[11];
  const float* Wk2 = (const float*)d_in[12]; const float* bk2 = (const float*)d_in[13];
  const float* Wv2 = (const float*)d_in[14]; const float* bv2 = (const float*)d_in[15];
  const float* Ws2 = (const float*)d_in[16]; const float* bs2 = (const float*)d_in[17];

  char* p = (char*)d_ws;
  auto take = [&](size_t bytes) { char* r = p; p += (bytes + 255) & ~(size_t)255; return r; };
  unsigned short* wbt = (unsigned short*)take((size_t)1024 * 384 * 2);
  float* bias1        = (float*)take(1024 * 4);
  char* qb8           = (char*)take((size_t)NPAD * 256);
  unsigned char* kvb  = (unsigned char*)take((size_t)NPAD * 512);
  unsigned short* s1b = (unsigned short*)take((size_t)NPAD * 256 * 2);
  unsigned short* w2bt = (unsigned short*)take(32 * 256 * 2);
  float* bias2        = (float*)take(32 * 4);
  float* qs2          = (float*)take((size_t)NPAD * 12 * 4);
  float* kv2          = (float*)take((size_t)NPAD * 12 * 4);
  int* counts         = (int*)take((size_t)(N_NODES + 64) * 4);   // +done counter
  int* scan_done      = counts + N_NODES;
  int* offsets        = (int*)take((size_t)(N_NODES + 1) * 4);
  int* cursor         = (int*)take((size_t)N_NODES * 4);
  int* csr_src        = (int*)take((size_t)N_EDGES * 4);
  int* scan_bsum      = (int*)take(256 * 4);

  hipMemsetAsync(counts, 0, (size_t)(N_NODES + 64) * 4, stream);
  prep_kernel<<<HIST_B + PW1_B + PW2_B, 256, 0, stream>>>(
      edst, counts, Wq1, Wk1, Wv1, Ws1, bq1, bk1, bv1, bs1, wbt, bias1,
      Wq2, Wk2, Wv2, Ws2, bq2, bk2, bv2, bs2, w2bt, bias2);
  scan_kernel<<<SCAN_B, 256, 0, stream>>>(counts, offsets, cursor, scan_bsum,
                                          scan_done, N_NODES, N_EDGES);
  gemm_scatter_kernel<<<GEMM_B + SCAT_B, 512, 0, stream>>>(
      x, wbt, bias1, qb8, kvb, s1b, esrc, edst, cursor, csr_src);
  agg1_kernel<<<2048, 256, 0, stream>>>(qb8, kvb, s1b, offsets, csr_src);
  lin2_kernel<<<NPAD / 128, 256, 0, stream>>>(s1b, w2bt, bias2, qs2, kv2);
  agg2_kernel<<<(N_NODES + 255) / 256, 256, 0, stream>>>(qs2, kv2, offsets, csr_src, (float*)d_out);
}

// Round 16
// 242.215 us; speedup vs baseline: 1.0721x; 1.0721x over previous
//
#include <hip/hip_runtime.h>
#include <hip/hip_bf16.h>

#define N_NODES 50000
#define N_EDGES 800000
#define NPAD    50048   // 391*128
#define SCAN_B  196     // ceil(50000/256)
#define HIST_B  3125    // 800000/256
#define PW1_B   1536    // 1024*384/256
#define PW2_B   32      // 32*256/256
#define GEMM_B  (((NPAD / 128 + 7) / 8) * 32)   // 1568
#define SCAT_B  ((N_EDGES + 511) / 512)         // 1563

typedef __attribute__((ext_vector_type(8))) short bf16x8;
typedef __attribute__((ext_vector_type(8))) unsigned short u16x8;
typedef __attribute__((ext_vector_type(4))) float f32x4;

__device__ __forceinline__ unsigned short f2bf(float f) {
  union { float f; unsigned u; } x; x.f = f;
  unsigned r = x.u + 0x7fffu + ((x.u >> 16) & 1u);
  return (unsigned short)(r >> 16);
}
__device__ __forceinline__ float bf2f(unsigned short u) {
  union { unsigned u; float f; } x; x.u = ((unsigned)u) << 16;
  return x.f;
}
// pack two floats -> 2xbf16 word (RNE; compiler emits v_cvt_pk_bf16_f32)
__device__ __forceinline__ unsigned pkbf(float lo, float hi) {
  return ((unsigned)f2bf(hi) << 16) | f2bf(lo);
}
// v: biased u8, scale 16: b = clamp(round(v*16)+128, 0,255); v = (b-128)/16
__device__ __forceinline__ unsigned char enc8v(float v) {
  float t = fminf(fmaxf(fmaf(v, 16.f, 128.5f), 0.f), 255.f);
  return (unsigned char)(int)t;
}
// k: signed i8, scale 16
__device__ __forceinline__ char enc8k(float v) {
  float t = fminf(fmaxf(v * 16.f, -127.f), 127.f);
  return (char)(int)floorf(t + 0.5f);
}
// q: signed i8, scale 24 (clip at |q|>5.29 -- ~1 element in 12.8M)
__device__ __forceinline__ char enc8q(float v) {
  float t = fminf(fmaxf(v * 24.f, -127.f), 127.f);
  return (char)(int)floorf(t + 0.5f);
}

__device__ __forceinline__ int dot4i8(int a, int b, int c) {
#if __has_builtin(__builtin_amdgcn_sdot4)
  return __builtin_amdgcn_sdot4(a, b, c, false);
#else
  int r = c;
  r += (int)(char)(a) * (int)(char)(b);
  r += (int)(char)(a >> 8) * (int)(char)(b >> 8);
  r += (int)(char)(a >> 16) * (int)(char)(b >> 16);
  r += (int)(char)(a >> 24) * (int)(char)(b >> 24);
  return r;
#endif
}

// async global->LDS, 16B per lane (dest must be linear: base + lane*16)
__device__ __forceinline__ void gload16(const void* g, void* l) {
  __builtin_amdgcn_global_load_lds(
      (const __attribute__((address_space(1))) unsigned int*)g,
      (__attribute__((address_space(3))) unsigned int*)l, 16, 0, 0);
}

// ---------------- fused CSR scan (single dispatch; 196 co-resident blocks) ----------------
__global__ __launch_bounds__(256) void scan_kernel(const int* __restrict__ counts,
                                                   int* __restrict__ offsets,
                                                   int* __restrict__ cursor,
                                                   int* __restrict__ bsum,
                                                   int* __restrict__ done,
                                                   int n, int E) {
  __shared__ int sm[256];
  int i = blockIdx.x * 256 + threadIdx.x;
  int v = (i < n) ? counts[i] : 0;
  sm[threadIdx.x] = v;
  __syncthreads();
  for (int off = 1; off < 256; off <<= 1) {
    int t = (threadIdx.x >= off) ? sm[threadIdx.x - off] : 0;
    __syncthreads();
    sm[threadIdx.x] += t;
    __syncthreads();
  }
  int local_ex = sm[threadIdx.x] - v;
  if (threadIdx.x == 255) {
    bsum[blockIdx.x] = sm[255];
    __threadfence();                 // publish bsum device-wide
    atomicAdd(done, 1);
  }
  if (threadIdx.x == 0) {
    while (atomicAdd(done, 0) < (int)gridDim.x) { }   // all blocks published
  }
  __syncthreads();
  int base = 0;
  for (int jj = threadIdx.x; jj < (int)blockIdx.x; jj += 256)
    base += atomicAdd(&bsum[jj], 0); // coherent read
  sm[threadIdx.x] = base;
  __syncthreads();
  for (int off = 128; off > 0; off >>= 1) {
    if (threadIdx.x < off) sm[threadIdx.x] += sm[threadIdx.x + off];
    __syncthreads();
  }
  base = sm[0];
  if (i < n) {
    int o = base + local_ex;
    offsets[i] = o;
    cursor[i] = o;
  }
  if (i == 0) offsets[n] = E;
}

// ---------------- fused prep: hist + pack_w1 + pack_w2 ----------------
__global__ __launch_bounds__(256) void prep_kernel(
    const int* __restrict__ edst, int* __restrict__ counts,
    const float* __restrict__ Wq1, const float* __restrict__ Wk1,
    const float* __restrict__ Wv1, const float* __restrict__ Ws1,
    const float* __restrict__ bq1, const float* __restrict__ bk1,
    const float* __restrict__ bv1, const float* __restrict__ bs1,
    unsigned short* __restrict__ wbt, float* __restrict__ bias1,
    const float* __restrict__ Wq2, const float* __restrict__ Wk2,
    const float* __restrict__ Wv2, const float* __restrict__ Ws2,
    const float* __restrict__ bq2, const float* __restrict__ bk2,
    const float* __restrict__ bv2, const float* __restrict__ bs2,
    unsigned short* __restrict__ w2bt, float* __restrict__ bias2) {
  int b = blockIdx.x;
  if (b < HIST_B) {
    int e = b * 256 + threadIdx.x;
    if (e < N_EDGES) atomicAdd(&counts[edst[e]], 1);
  } else if (b < HIST_B + PW1_B) {
    int idx = (b - HIST_B) * 256 + threadIdx.x;
    int n = idx / 384, k = idx - n * 384;
    int blk = n >> 8, cc = n & 255;
    const float* W = (blk == 0) ? Wq1 : (blk == 1) ? Wk1 : (blk == 2) ? Wv1 : Ws1;
    wbt[idx] = f2bf(W[(long)k * 256 + cc]);   // wbt[n][k] = W[k][cc] (transposed)
    if (k == 0) {
      const float* bb = (blk == 0) ? bq1 : (blk == 1) ? bk1 : (blk == 2) ? bv1 : bs1;
      bias1[n] = bb[cc];
    }
  } else {
    int idx = (b - HIST_B - PW1_B) * 256 + threadIdx.x;
    int c = idx >> 8, p = idx & 255;
    unsigned short o = 0;
    if (c < 20) {
      int blk = c / 5, cc = c - blk * 5;
      int tch = (p & 0xC0) + (p & 3) * 16 + ((p & 63) >> 2);   // inverse permutation
      const float* W = (blk == 0) ? Wq2 : (blk == 1) ? Wk2 : (blk == 2) ? Wv2 : Ws2;
      o = f2bf(W[(long)tch * 5 + cc]);
      if (p == 0) {
        const float* bb = (blk == 0) ? bq2 : (blk == 1) ? bk2 : (blk == 2) ? bv2 : bs2;
        bias2[c] = bb[cc];
      }
    }
    w2bt[idx] = o;
  }
}

// ---------------- layer-1 fused QKVS GEMM + edge scatter (R14 measured-best) ----------------
// bid < GEMM_B: GEMM. BK=64, 48KB single-buffer LDS, A reg-staged fp32 with
// post-barrier prefetch, B via global_load_lds. 0 bank conflicts.
// bid >= GEMM_B: CSR edge scatter (overlaps under the GEMM).
// y=0 q i8(24); y=1 k i8(16); y=2 v u8-biased; y=3 skip bf16; permuted channels.
// 1D grid XCD-grouped: 4 y-blocks of one m-panel share bid%8 -> same XCD L2.
__global__ __launch_bounds__(512) void gemm_scatter_kernel(
    const float* __restrict__ x, const unsigned short* __restrict__ wbt,
    const float* __restrict__ bias,
    char* __restrict__ qb8, unsigned char* __restrict__ kvb,
    unsigned short* __restrict__ s1b,
    const int* __restrict__ esrc, const int* __restrict__ edst,
    int* __restrict__ cursor, int* __restrict__ csr_src) {
  __shared__ unsigned short As[128 * 64];   // 16 KB
  __shared__ unsigned short Bs[256 * 64];   // 32 KB
  int bid = blockIdx.x;
  if (bid >= GEMM_B) {                      // ---- scatter tail ----
    int e = (bid - GEMM_B) * 512 + threadIdx.x;
    if (e < N_EDGES) {
      int pos = atomicAdd(&cursor[edst[e]], 1);
      csr_src[pos] = esrc[e];
    }
    return;
  }
  int grp = bid >> 5, bl = bid & 31;
  int mx = grp * 8 + (bl & 7);
  int y = bl >> 3;
  if (mx >= NPAD / 128) return;   // uniform per block
  int tid = threadIdx.x;
  long m0 = (long)mx * 128;
  int n0 = y * 256;
  int w = tid >> 6, l = tid & 63;
  int wr = (w >> 2) * 64, wc = (w & 3) * 64;
  int lr = l & 15, c0 = l >> 4;
  int lj = lr & 7;                          // (fragment row)&7, all mf/nf alike
  f32x4 acc[4][4] = {};
  // A staging: thread -> rows ra and ra+64, LDS chunk cs=tid&7,
  // source chunk cg = cs ^ (ra&7)  ((ra+64)&7 == ra&7).
  int ra = tid >> 3, cs = tid & 7;
  int cg = cs ^ (ra & 7);
  long ar0 = m0 + ra;      if (ar0 > (long)(N_NODES - 1)) ar0 = N_NODES - 1;
  long ar1 = m0 + 64 + ra; if (ar1 > (long)(N_NODES - 1)) ar1 = N_NODES - 1;
  const float* gA0 = x + ar0 * 384 + cg * 8;
  const float* gA1 = x + ar1 * 384 + cg * 8;
  unsigned short* aw0 = &As[ra * 64 + cs * 8];
  unsigned short* aw1 = &As[(ra + 64) * 64 + cs * 8];
  // B staging: 4 gload16/thread; row (tid>>3)+r*64, LDS chunk cs,
  // source chunk = cs ^ (row&7) (row&7 == ra&7 for all r).
  const unsigned short* gB[4];
#pragma unroll
  for (int r = 0; r < 4; ++r)
    gB[r] = wbt + (long)(n0 + ra + r * 64) * 384 + cg * 8;
  // prologue: A regs for kt=0
  float4 a00 = *(const float4*)gA0, a01 = *(const float4*)(gA0 + 4);
  float4 a10 = *(const float4*)gA1, a11 = *(const float4*)(gA1 + 4);
  for (int kt = 0; kt < 6; ++kt) {
    int ko = kt * 64;
    __syncthreads();   // barrier1: LDS consumed; A-reg prefetch drained here
#pragma unroll
    for (int r = 0; r < 4; ++r)
      gload16(gB[r] + ko, &Bs[(tid + r * 512) * 8]);
    {
      union { bf16x8 v; unsigned u[4]; } t;
      t.u[0] = pkbf(a00.x, a00.y); t.u[1] = pkbf(a00.z, a00.w);
      t.u[2] = pkbf(a01.x, a01.y); t.u[3] = pkbf(a01.z, a01.w);
      *(bf16x8*)aw0 = t.v;
      t.u[0] = pkbf(a10.x, a10.y); t.u[1] = pkbf(a10.z, a10.w);
      t.u[2] = pkbf(a11.x, a11.y); t.u[3] = pkbf(a11.z, a11.w);
      *(bf16x8*)aw1 = t.v;
    }
    __syncthreads();   // barrier2: drains B gloads + A ds_writes
    if (kt < 5) {      // A prefetch AFTER barrier2: hides under MFMA phase
      a00 = *(const float4*)(gA0 + ko + 64); a01 = *(const float4*)(gA0 + ko + 68);
      a10 = *(const float4*)(gA1 + ko + 64); a11 = *(const float4*)(gA1 + ko + 68);
    }
#pragma unroll
    for (int ks = 0; ks < 2; ++ks) {
      int pc = ((ks * 4 + c0) ^ lj) * 8;   // physical chunk offset (elements)
      bf16x8 af[4], bfv[4];
#pragma unroll
      for (int mf = 0; mf < 4; ++mf)
        af[mf] = *(const bf16x8*)&As[(wr + mf * 16 + lr) * 64 + pc];
#pragma unroll
      for (int nf = 0; nf < 4; ++nf)
        bfv[nf] = *(const bf16x8*)&Bs[(wc + nf * 16 + lr) * 64 + pc];
#pragma unroll
      for (int mf = 0; mf < 4; ++mf)
#pragma unroll
        for (int nf = 0; nf < 4; ++nf)
          acc[mf][nf] = __builtin_amdgcn_mfma_f32_16x16x32_bf16(af[mf], bfv[nf], acc[mf][nf], 0, 0, 0);
    }
  }
  float bv[4];
#pragma unroll
  for (int nf = 0; nf < 4; ++nf) bv[nf] = bias[n0 + wc + nf * 16 + lr];
  int pos = wc + lr * 4;
#pragma unroll
  for (int mf = 0; mf < 4; ++mf) {
#pragma unroll
    for (int i = 0; i < 4; ++i) {
      long row = m0 + wr + mf * 16 + c0 * 4 + i;
      float v0 = acc[mf][0][i] + bv[0];
      float v1 = acc[mf][1][i] + bv[1];
      float v2 = acc[mf][2][i] + bv[2];
      float v3 = acc[mf][3][i] + bv[3];
      if (y == 0) {
        char4 st; st.x = enc8q(v0); st.y = enc8q(v1); st.z = enc8q(v2); st.w = enc8q(v3);
        *(char4*)&qb8[row * 256 + pos] = st;
      } else if (y == 1) {
        char4 st; st.x = enc8k(v0); st.y = enc8k(v1); st.z = enc8k(v2); st.w = enc8k(v3);
        *(char4*)&kvb[row * 512 + pos] = st;
      } else if (y == 2) {
        uchar4 st; st.x = enc8v(v0); st.y = enc8v(v1); st.z = enc8v(v2); st.w = enc8v(v3);
        *(uchar4*)&kvb[row * 512 + 256 + pos] = st;
      } else {
        ushort4 st; st.x = f2bf(v0); st.y = f2bf(v1); st.z = f2bf(v2); st.w = f2bf(v3);
        *(ushort4*)&s1b[row * 256 + pos] = st;
      }
    }
  }
}

// ---------------- layer-1 fused attention aggregation (i8 kv, sdot4, pipelined) ----------------
__global__ __launch_bounds__(256) void agg1_kernel(
    const char* __restrict__ qb8, const unsigned char* __restrict__ kvb,
    unsigned short* s1b,
    const int* __restrict__ offsets, const int* __restrict__ csr_src) {
  int w = threadIdx.x >> 6, l = threadIdx.x & 63;
  int g = l >> 4;            // edge slot 0..3
  int sub = l & 15;          // channel block (head = sub>>2)
  for (int n = blockIdx.x * 4 + w; n < N_NODES; n += gridDim.x * 4) {
    int i0 = offsets[n], i1 = offsets[n + 1];
    long ob = (long)n * 256 + sub * 16;
    if (i0 >= i1) {          // deg-0: h = relu(skip)
      if (g == 0) {
        u16x8 sv0 = *(const u16x8*)&s1b[ob];
        u16x8 sv1 = *(const u16x8*)&s1b[ob + 8];
        u16x8 h0, h1;
#pragma unroll
        for (int j = 0; j < 8; ++j) {
          h0[j] = (short)f2bf(fmaxf(bf2f((unsigned short)sv0[j]), 0.f));
          h1[j] = (short)f2bf(fmaxf(bf2f((unsigned short)sv1[j]), 0.f));
        }
        *(u16x8*)&s1b[ob] = h0;
        *(u16x8*)&s1b[ob + 8] = h1;
      }
      continue;
    }
    int4 qi = *(const int4*)&qb8[(long)n * 256 + sub * 16];
    float acc[16] = {};
    float se = 0.f;

    auto ldbatch = [&](int i, int4& ka, uint4& va, int4& kw, uint4& vw) {
      int ia = i + g, ib = i + 4 + g;
      int sa = csr_src[ia < i1 ? ia : i1 - 1];
      int sb = csr_src[ib < i1 ? ib : i1 - 1];
      const char* ba = (const char*)kvb + (long)sa * 512 + sub * 16;
      const char* bb = (const char*)kvb + (long)sb * 512 + sub * 16;
      ka = *(const int4*)ba; va = *(const uint4*)(ba + 256);
      kw = *(const int4*)bb; vw = *(const uint4*)(bb + 256);
    };
#define VACC(E, W, B) \
    acc[(B) + 0] = fmaf(E, (float)((W) & 0xffu), acc[(B) + 0]); \
    acc[(B) + 1] = fmaf(E, (float)(((W) >> 8) & 0xffu), acc[(B) + 1]); \
    acc[(B) + 2] = fmaf(E, (float)(((W) >> 16) & 0xffu), acc[(B) + 2]); \
    acc[(B) + 3] = fmaf(E, (float)((W) >> 24), acc[(B) + 3]);
    auto consume = [&](int i, int4 ka, uint4 va, int4 kw, uint4 vw) {
      int ia = i + g, ib = i + 4 + g;
      int da = 0, db = 0;
      da = dot4i8(qi.x, ka.x, da); da = dot4i8(qi.y, ka.y, da);
      da = dot4i8(qi.z, ka.z, da); da = dot4i8(qi.w, ka.w, da);
      db = dot4i8(qi.x, kw.x, db); db = dot4i8(qi.y, kw.y, db);
      db = dot4i8(qi.z, kw.z, db); db = dot4i8(qi.w, kw.w, db);
      da += __shfl_xor(da, 1); da += __shfl_xor(da, 2);
      db += __shfl_xor(db, 1); db += __shfl_xor(db, 2);
      float ea = (ia < i1) ? __expf((float)da * (1.f / 3072.f)) : 0.f;
      float eb = (ib < i1) ? __expf((float)db * (1.f / 3072.f)) : 0.f;
      se += ea + eb;
      VACC(ea, va.x, 0) VACC(ea, va.y, 4) VACC(ea, va.z, 8) VACC(ea, va.w, 12)
      VACC(eb, vw.x, 0) VACC(eb, vw.y, 4) VACC(eb, vw.z, 8) VACC(eb, vw.w, 12)
    };

    int i = i0;
    int4 ka0, kw0; uint4 va0, vw0;
    ldbatch(i, ka0, va0, kw0, vw0);
    for (; i + 8 < i1; i += 8) {
      int4 ka1, kw1; uint4 va1, vw1;
      ldbatch(i + 8, ka1, va1, kw1, vw1);     // prefetch next batch
      consume(i, ka0, va0, kw0, vw0);
      ka0 = ka1; va0 = va1; kw0 = kw1; vw0 = vw1;
    }
    consume(i, ka0, va0, kw0, vw0);
#undef VACC
#pragma unroll
    for (int j = 0; j < 16; ++j) {
      acc[j] += __shfl_xor(acc[j], 16);
      acc[j] += __shfl_xor(acc[j], 32);
    }
    se += __shfl_xor(se, 16);
    se += __shfl_xor(se, 32);
    if (g == 0) {
      float inv = (se > 0.f) ? 1.0f / se : 0.f;
      float bias = (se > 0.f) ? -8.0f : 0.f;
      u16x8 sv0 = *(const u16x8*)&s1b[ob];
      u16x8 sv1 = *(const u16x8*)&s1b[ob + 8];
      u16x8 h0, h1;
#pragma unroll
      for (int j = 0; j < 8; ++j) {
        float v0 = fmaf(acc[j] * inv, 0.0625f, bias);
        float v1 = fmaf(acc[8 + j] * inv, 0.0625f, bias);
        h0[j] = (short)f2bf(fmaxf(v0 + bf2f((unsigned short)sv0[j]), 0.f));
        h1[j] = (short)f2bf(fmaxf(v1 + bf2f((unsigned short)sv1[j]), 0.f));
      }
      *(u16x8*)&s1b[ob] = h0;
      *(u16x8*)&s1b[ob + 8] = h1;
    }
  }
}

// ---------------- layer-2 linear via MFMA: [NPAD x 256] @ [256 x 32] ----------------
__global__ __launch_bounds__(256) void lin2_kernel(const unsigned short* __restrict__ hb,
                                                   const unsigned short* __restrict__ w2bt,
                                                   const float* __restrict__ bias2,
                                                   float* __restrict__ qs2, float* __restrict__ kv2) {
  __shared__ unsigned short Bs2[32 * 264];
  __shared__ float bsh[32];
  for (int i = threadIdx.x; i < 32 * 32; i += 256) {
    int r = i >> 5, cc = i & 31;
    *(u16x8*)&Bs2[r * 264 + cc * 8] = *(const u16x8*)&w2bt[r * 256 + cc * 8];
  }
  if (threadIdx.x < 32) bsh[threadIdx.x] = (threadIdx.x < 20) ? bias2[threadIdx.x] : 0.f;
  __syncthreads();
  int w = threadIdx.x >> 6, l = threadIdx.x & 63;
  long row0 = (long)blockIdx.x * 128 + w * 32;
  int lr = l & 15, c0 = l >> 4;
  f32x4 acc[2][2] = {};
  for (int kk = 0; kk < 8; ++kk) {
    int koff = kk * 32 + c0 * 8;
    bf16x8 af[2], bfv[2];
    af[0] = *(const bf16x8*)&hb[(row0 + lr) * 256 + koff];
    af[1] = *(const bf16x8*)&hb[(row0 + 16 + lr) * 256 + koff];
    bfv[0] = *(const bf16x8*)&Bs2[lr * 264 + koff];
    bfv[1] = *(const bf16x8*)&Bs2[(16 + lr) * 264 + koff];
#pragma unroll
    for (int mf = 0; mf < 2; ++mf)
#pragma unroll
      for (int nf = 0; nf < 2; ++nf)
        acc[mf][nf] = __builtin_amdgcn_mfma_f32_16x16x32_bf16(af[mf], bfv[nf], acc[mf][nf], 0, 0, 0);
  }
#pragma unroll
  for (int mf = 0; mf < 2; ++mf) {
#pragma unroll
    for (int nf = 0; nf < 2; ++nf) {
      int col = nf * 16 + lr;
#pragma unroll
      for (int i = 0; i < 4; ++i) {
        long n = row0 + mf * 16 + c0 * 4 + i;
        float v = acc[mf][nf][i] + bsh[col];
        if (col < 5) qs2[n * 12 + col] = v;
        else if (col < 15) kv2[n * 12 + (col - 5)] = v;
        else if (col < 20) qs2[n * 12 + (col - 10)] = v;
      }
    }
  }
}

// ---------------- layer-2 fused attention (1 thread per node) ----------------
__global__ void agg2_kernel(const float* __restrict__ qs2, const float* __restrict__ kv2,
                            const int* __restrict__ offsets, const int* __restrict__ csr_src,
                            float* __restrict__ out) {
  int n = blockIdx.x * 256 + threadIdx.x;
  if (n >= N_NODES) return;
  const float* bn = &qs2[(long)n * 12];
  const float is5 = 0.4472135954999579f;  // 1/sqrt(5)
  float q[5], acc[5] = {0, 0, 0, 0, 0}, se = 0.f;
#pragma unroll
  for (int c = 0; c < 5; ++c) q[c] = bn[c] * is5;
  int i0 = offsets[n], i1 = offsets[n + 1];
  for (int i = i0; i < i1; ++i) {
    int s = csr_src[i];
    const float4* ps = (const float4*)&kv2[(long)s * 12];
    float4 A = ps[0], B = ps[1], C = ps[2];
    float lg = q[0] * A.x + q[1] * A.y + q[2] * A.z + q[3] * A.w + q[4] * B.x;
    float ee = __expf(lg);
    se += ee;
    acc[0] += ee * B.y; acc[1] += ee * B.z; acc[2] += ee * B.w;
    acc[3] += ee * C.x; acc[4] += ee * C.y;
  }
  float inv = 1.f / (se + 1e-16f);
#pragma unroll
  for (int c = 0; c < 5; ++c) out[(long)n * 5 + c] = acc[c] * inv + bn[5 + c];
}

// ---------------- launch ----------------
extern "C" void kernel_launch(void* const* d_in, const int* in_sizes, int n_in,
                              void* d_out, int out_size, void* d_ws, size_t ws_size,
                              hipStream_t stream) {
  (void)in_sizes; (void)n_in; (void)out_size; (void)ws_size;
  const float* x   = (const float*)d_in[0];
  const int* eidx  = (const int*)d_in[1];
  const int* esrc  = eidx;
  const int* edst  = eidx + N_EDGES;
  const float* Wq1 = (const float*)d_in[2];  const float* bq1 = (const float*)d_in[3];
  const float* Wk1 = (const float*)d_in[4];  const float* bk1 = (const float*)d_in[5];
  const float* Wv1 = (const float*)d_in[6];  const float* bv1 = (const float*)d_in[7];
  const float* Ws1 = (const float*)d_in[8];  const float* bs1 = (const float*)d_in[9];
  const float* Wq2 = (const float*)d_in[10]; const float* bq2 = (const float*)d_in[11];
  const float* Wk2 = (const float*)d_in[12]; const float* bk2 = (const float*)d_in[13];
  const float* Wv2 = (const float*)d_in[14]; const float* bv2 = (const float*)d_in[15];
  const float* Ws2 = (const float*)d_in[16]; const float* bs2 = (const float*)d_in[17];

  char* p = (char*)d_ws;
  auto take = [&](size_t bytes) { char* r = p; p += (bytes + 255) & ~(size_t)255; return r; };
  unsigned short* wbt = (unsigned short*)take((size_t)1024 * 384 * 2);
  float* bias1        = (float*)take(1024 * 4);
  char* qb8           = (char*)take((size_t)NPAD * 256);
  unsigned char* kvb  = (unsigned char*)take((size_t)NPAD * 512);
  unsigned short* s1b = (unsigned short*)take((size_t)NPAD * 256 * 2);
  unsigned short* w2bt = (unsigned short*)take(32 * 256 * 2);
  float* bias2        = (float*)take(32 * 4);
  float* qs2          = (float*)take((size_t)NPAD * 12 * 4);
  float* kv2          = (float*)take((size_t)NPAD * 12 * 4);
  int* counts         = (int*)take((size_t)(N_NODES + 64) * 4);   // +done counter
  int* scan_done      = counts + N_NODES;
  int* offsets        = (int*)take((size_t)(N_NODES + 1) * 4);
  int* cursor         = (int*)take((size_t)N_NODES * 4);
  int* csr_src        = (int*)take((size_t)N_EDGES * 4);
  int* scan_bsum      = (int*)take(256 * 4);

  hipMemsetAsync(counts, 0, (size_t)(N_NODES + 64) * 4, stream);
  prep_kernel<<<HIST_B + PW1_B + PW2_B, 256, 0, stream>>>(
      edst, counts, Wq1, Wk1, Wv1, Ws1, bq1, bk1, bv1, bs1, wbt, bias1,
      Wq2, Wk2, Wv2, Ws2, bq2, bk2, bv2, bs2, w2bt, bias2);
  scan_kernel<<<SCAN_B, 256, 0, stream>>>(counts, offsets, cursor, scan_bsum,
                                          scan_done, N_NODES, N_EDGES);
  gemm_scatter_kernel<<<GEMM_B + SCAT_B, 512, 0, stream>>>(
      x, wbt, bias1, qb8, kvb, s1b, esrc, edst, cursor, csr_src);
  agg1_kernel<<<2048, 256, 0, stream>>>(qb8, kvb, s1b, offsets, csr_src);
  lin2_kernel<<<NPAD / 128, 256, 0, stream>>>(s1b, w2bt, bias2, qs2, kv2);
  agg2_kernel<<<(N_NODES + 255) / 256, 256, 0, stream>>>(qs2, kv2, offsets, csr_src, (float*)d_out);
}

// Round 17
// 234.881 us; speedup vs baseline: 1.1055x; 1.0312x over previous
//
#include <hip/hip_runtime.h>
#include <hip/hip_bf16.h>

#define N_NODES 50000
#define N_EDGES 800000
#define NPAD    50048   // 391*128
#define SCAN_B  196     // ceil(50000/256)
#define HIST_B  3125    // 800000/256
#define PW1_B   1536    // 1024*384/256
#define PW2_B   32      // 32*256/256
#define GEMM_B  (((NPAD / 128 + 7) / 8) * 32)   // 1568
#define SCAT_B  ((N_EDGES + 511) / 512)         // 1563

typedef __attribute__((ext_vector_type(8))) short bf16x8;
typedef __attribute__((ext_vector_type(8))) unsigned short u16x8;
typedef __attribute__((ext_vector_type(4))) float f32x4;

__device__ __forceinline__ unsigned short f2bf(float f) {
  union { float f; unsigned u; } x; x.f = f;
  unsigned r = x.u + 0x7fffu + ((x.u >> 16) & 1u);
  return (unsigned short)(r >> 16);
}
__device__ __forceinline__ float bf2f(unsigned short u) {
  union { unsigned u; float f; } x; x.u = ((unsigned)u) << 16;
  return x.f;
}
// pack two floats -> 2xbf16 word (RNE; compiler emits v_cvt_pk_bf16_f32)
__device__ __forceinline__ unsigned pkbf(float lo, float hi) {
  return ((unsigned)f2bf(hi) << 16) | f2bf(lo);
}
// v: biased u8, scale 16: b = clamp(round(v*16)+128, 0,255); v = (b-128)/16
__device__ __forceinline__ unsigned char enc8v(float v) {
  float t = fminf(fmaxf(fmaf(v, 16.f, 128.5f), 0.f), 255.f);
  return (unsigned char)(int)t;
}
// k: signed i8, scale 16
__device__ __forceinline__ char enc8k(float v) {
  float t = fminf(fmaxf(v * 16.f, -127.f), 127.f);
  return (char)(int)floorf(t + 0.5f);
}
// q: signed i8, scale 24 (clip at |q|>5.29 -- ~1 element in 12.8M)
__device__ __forceinline__ char enc8q(float v) {
  float t = fminf(fmaxf(v * 24.f, -127.f), 127.f);
  return (char)(int)floorf(t + 0.5f);
}

__device__ __forceinline__ int dot4i8(int a, int b, int c) {
#if __has_builtin(__builtin_amdgcn_sdot4)
  return __builtin_amdgcn_sdot4(a, b, c, false);
#else
  int r = c;
  r += (int)(char)(a) * (int)(char)(b);
  r += (int)(char)(a >> 8) * (int)(char)(b >> 8);
  r += (int)(char)(a >> 16) * (int)(char)(b >> 16);
  r += (int)(char)(a >> 24) * (int)(char)(b >> 24);
  return r;
#endif
}

// async global->LDS, 16B per lane (dest must be linear: base + lane*16)
__device__ __forceinline__ void gload16(const void* g, void* l) {
  __builtin_amdgcn_global_load_lds(
      (const __attribute__((address_space(1))) unsigned int*)g,
      (__attribute__((address_space(3))) unsigned int*)l, 16, 0, 0);
}

// ---------------- CSR build (3-kernel scan, measured-best) ----------------
__global__ __launch_bounds__(256) void scan1_kernel(const int* __restrict__ counts,
                                                    int* __restrict__ tmp, int* __restrict__ bsum, int n) {
  __shared__ int sm[256];
  int i = blockIdx.x * 256 + threadIdx.x;
  int v = (i < n) ? counts[i] : 0;
  sm[threadIdx.x] = v;
  __syncthreads();
  for (int off = 1; off < 256; off <<= 1) {
    int t = (threadIdx.x >= off) ? sm[threadIdx.x - off] : 0;
    __syncthreads();
    sm[threadIdx.x] += t;
    __syncthreads();
  }
  if (i < n) tmp[i] = sm[threadIdx.x] - v;
  if (threadIdx.x == 255) bsum[blockIdx.x] = sm[255];
}

__global__ __launch_bounds__(256) void scan2_kernel(const int* __restrict__ bsum,
                                                    int* __restrict__ bbase, int nb) {
  __shared__ int sm[256];
  int v = (threadIdx.x < nb) ? bsum[threadIdx.x] : 0;
  sm[threadIdx.x] = v;
  __syncthreads();
  for (int off = 1; off < 256; off <<= 1) {
    int t = (threadIdx.x >= off) ? sm[threadIdx.x - off] : 0;
    __syncthreads();
    sm[threadIdx.x] += t;
    __syncthreads();
  }
  if (threadIdx.x < nb) bbase[threadIdx.x] = sm[threadIdx.x] - v;
}

__global__ __launch_bounds__(256) void scan3_kernel(const int* __restrict__ tmp,
                                                    const int* __restrict__ bbase,
                                                    int* __restrict__ offsets, int* __restrict__ cursor,
                                                    int n, int E) {
  int i = blockIdx.x * 256 + threadIdx.x;
  if (i < n) {
    int o = tmp[i] + bbase[blockIdx.x];
    offsets[i] = o;
    cursor[i] = o;
  }
  if (i == 0) offsets[n] = E;
}

// ---------------- fused prep: hist + pack_w1 + pack_w2 ----------------
__global__ __launch_bounds__(256) void prep_kernel(
    const int* __restrict__ edst, int* __restrict__ counts,
    const float* __restrict__ Wq1, const float* __restrict__ Wk1,
    const float* __restrict__ Wv1, const float* __restrict__ Ws1,
    const float* __restrict__ bq1, const float* __restrict__ bk1,
    const float* __restrict__ bv1, const float* __restrict__ bs1,
    unsigned short* __restrict__ wbt, float* __restrict__ bias1,
    const float* __restrict__ Wq2, const float* __restrict__ Wk2,
    const float* __restrict__ Wv2, const float* __restrict__ Ws2,
    const float* __restrict__ bq2, const float* __restrict__ bk2,
    const float* __restrict__ bv2, const float* __restrict__ bs2,
    unsigned short* __restrict__ w2bt, float* __restrict__ bias2) {
  int b = blockIdx.x;
  if (b < HIST_B) {
    int e = b * 256 + threadIdx.x;
    if (e < N_EDGES) atomicAdd(&counts[edst[e]], 1);
  } else if (b < HIST_B + PW1_B) {
    int idx = (b - HIST_B) * 256 + threadIdx.x;
    int n = idx / 384, k = idx - n * 384;
    int blk = n >> 8, cc = n & 255;
    const float* W = (blk == 0) ? Wq1 : (blk == 1) ? Wk1 : (blk == 2) ? Wv1 : Ws1;
    wbt[idx] = f2bf(W[(long)k * 256 + cc]);   // wbt[n][k] = W[k][cc] (transposed)
    if (k == 0) {
      const float* bb = (blk == 0) ? bq1 : (blk == 1) ? bk1 : (blk == 2) ? bv1 : bs1;
      bias1[n] = bb[cc];
    }
  } else {
    int idx = (b - HIST_B - PW1_B) * 256 + threadIdx.x;
    int c = idx >> 8, p = idx & 255;
    unsigned short o = 0;
    if (c < 20) {
      int blk = c / 5, cc = c - blk * 5;
      int tch = (p & 0xC0) + (p & 3) * 16 + ((p & 63) >> 2);   // inverse permutation
      const float* W = (blk == 0) ? Wq2 : (blk == 1) ? Wk2 : (blk == 2) ? Wv2 : Ws2;
      o = f2bf(W[(long)tch * 5 + cc]);
      if (p == 0) {
        const float* bb = (blk == 0) ? bq2 : (blk == 1) ? bk2 : (blk == 2) ? bv2 : bs2;
        bias2[c] = bb[cc];
      }
    }
    w2bt[idx] = o;
  }
}

// ---------------- layer-1 fused QKVS GEMM + edge scatter (R14 measured-best) ----------------
// bid < GEMM_B: GEMM. BK=64, 48KB single-buffer LDS, A reg-staged fp32 with
// post-barrier prefetch, B via global_load_lds. 0 bank conflicts.
// bid >= GEMM_B: CSR edge scatter (overlaps under the GEMM).
// y=0 q i8(24); y=1 k i8(16); y=2 v u8-biased; y=3 skip bf16; permuted channels.
// 1D grid XCD-grouped: 4 y-blocks of one m-panel share bid%8 -> same XCD L2.
__global__ __launch_bounds__(512) void gemm_scatter_kernel(
    const float* __restrict__ x, const unsigned short* __restrict__ wbt,
    const float* __restrict__ bias,
    char* __restrict__ qb8, unsigned char* __restrict__ kvb,
    unsigned short* __restrict__ s1b,
    const int* __restrict__ esrc, const int* __restrict__ edst,
    int* __restrict__ cursor, int* __restrict__ csr_src) {
  __shared__ unsigned short As[128 * 64];   // 16 KB
  __shared__ unsigned short Bs[256 * 64];   // 32 KB
  int bid = blockIdx.x;
  if (bid >= GEMM_B) {                      // ---- scatter tail ----
    int e = (bid - GEMM_B) * 512 + threadIdx.x;
    if (e < N_EDGES) {
      int pos = atomicAdd(&cursor[edst[e]], 1);
      csr_src[pos] = esrc[e];
    }
    return;
  }
  int grp = bid >> 5, bl = bid & 31;
  int mx = grp * 8 + (bl & 7);
  int y = bl >> 3;
  if (mx >= NPAD / 128) return;   // uniform per block
  int tid = threadIdx.x;
  long m0 = (long)mx * 128;
  int n0 = y * 256;
  int w = tid >> 6, l = tid & 63;
  int wr = (w >> 2) * 64, wc = (w & 3) * 64;
  int lr = l & 15, c0 = l >> 4;
  int lj = lr & 7;                          // (fragment row)&7, all mf/nf alike
  f32x4 acc[4][4] = {};
  // A staging: thread -> rows ra and ra+64, LDS chunk cs=tid&7,
  // source chunk cg = cs ^ (ra&7)  ((ra+64)&7 == ra&7).
  int ra = tid >> 3, cs = tid & 7;
  int cg = cs ^ (ra & 7);
  long ar0 = m0 + ra;      if (ar0 > (long)(N_NODES - 1)) ar0 = N_NODES - 1;
  long ar1 = m0 + 64 + ra; if (ar1 > (long)(N_NODES - 1)) ar1 = N_NODES - 1;
  const float* gA0 = x + ar0 * 384 + cg * 8;
  const float* gA1 = x + ar1 * 384 + cg * 8;
  unsigned short* aw0 = &As[ra * 64 + cs * 8];
  unsigned short* aw1 = &As[(ra + 64) * 64 + cs * 8];
  // B staging: 4 gload16/thread; row (tid>>3)+r*64, LDS chunk cs,
  // source chunk = cs ^ (row&7) (row&7 == ra&7 for all r).
  const unsigned short* gB[4];
#pragma unroll
  for (int r = 0; r < 4; ++r)
    gB[r] = wbt + (long)(n0 + ra + r * 64) * 384 + cg * 8;
  // prologue: A regs for kt=0
  float4 a00 = *(const float4*)gA0, a01 = *(const float4*)(gA0 + 4);
  float4 a10 = *(const float4*)gA1, a11 = *(const float4*)(gA1 + 4);
  for (int kt = 0; kt < 6; ++kt) {
    int ko = kt * 64;
    __syncthreads();   // barrier1: LDS consumed; A-reg prefetch drained here
#pragma unroll
    for (int r = 0; r < 4; ++r)
      gload16(gB[r] + ko, &Bs[(tid + r * 512) * 8]);
    {
      union { bf16x8 v; unsigned u[4]; } t;
      t.u[0] = pkbf(a00.x, a00.y); t.u[1] = pkbf(a00.z, a00.w);
      t.u[2] = pkbf(a01.x, a01.y); t.u[3] = pkbf(a01.z, a01.w);
      *(bf16x8*)aw0 = t.v;
      t.u[0] = pkbf(a10.x, a10.y); t.u[1] = pkbf(a10.z, a10.w);
      t.u[2] = pkbf(a11.x, a11.y); t.u[3] = pkbf(a11.z, a11.w);
      *(bf16x8*)aw1 = t.v;
    }
    __syncthreads();   // barrier2: drains B gloads + A ds_writes
    if (kt < 5) {      // A prefetch AFTER barrier2: hides under MFMA phase
      a00 = *(const float4*)(gA0 + ko + 64); a01 = *(const float4*)(gA0 + ko + 68);
      a10 = *(const float4*)(gA1 + ko + 64); a11 = *(const float4*)(gA1 + ko + 68);
    }
#pragma unroll
    for (int ks = 0; ks < 2; ++ks) {
      int pc = ((ks * 4 + c0) ^ lj) * 8;   // physical chunk offset (elements)
      bf16x8 af[4], bfv[4];
#pragma unroll
      for (int mf = 0; mf < 4; ++mf)
        af[mf] = *(const bf16x8*)&As[(wr + mf * 16 + lr) * 64 + pc];
#pragma unroll
      for (int nf = 0; nf < 4; ++nf)
        bfv[nf] = *(const bf16x8*)&Bs[(wc + nf * 16 + lr) * 64 + pc];
#pragma unroll
      for (int mf = 0; mf < 4; ++mf)
#pragma unroll
        for (int nf = 0; nf < 4; ++nf)
          acc[mf][nf] = __builtin_amdgcn_mfma_f32_16x16x32_bf16(af[mf], bfv[nf], acc[mf][nf], 0, 0, 0);
    }
  }
  float bv[4];
#pragma unroll
  for (int nf = 0; nf < 4; ++nf) bv[nf] = bias[n0 + wc + nf * 16 + lr];
  int pos = wc + lr * 4;
#pragma unroll
  for (int mf = 0; mf < 4; ++mf) {
#pragma unroll
    for (int i = 0; i < 4; ++i) {
      long row = m0 + wr + mf * 16 + c0 * 4 + i;
      float v0 = acc[mf][0][i] + bv[0];
      float v1 = acc[mf][1][i] + bv[1];
      float v2 = acc[mf][2][i] + bv[2];
      float v3 = acc[mf][3][i] + bv[3];
      if (y == 0) {
        char4 st; st.x = enc8q(v0); st.y = enc8q(v1); st.z = enc8q(v2); st.w = enc8q(v3);
        *(char4*)&qb8[row * 256 + pos] = st;
      } else if (y == 1) {
        char4 st; st.x = enc8k(v0); st.y = enc8k(v1); st.z = enc8k(v2); st.w = enc8k(v3);
        *(char4*)&kvb[row * 512 + pos] = st;
      } else if (y == 2) {
        uchar4 st; st.x = enc8v(v0); st.y = enc8v(v1); st.z = enc8v(v2); st.w = enc8v(v3);
        *(uchar4*)&kvb[row * 512 + 256 + pos] = st;
      } else {
        ushort4 st; st.x = f2bf(v0); st.y = f2bf(v1); st.z = f2bf(v2); st.w = f2bf(v3);
        *(ushort4*)&s1b[row * 256 + pos] = st;
      }
    }
  }
}

// ---------------- layer-1 fused attention aggregation (i8 kv, sdot4, pipelined) ----------------
__global__ __launch_bounds__(256) void agg1_kernel(
    const char* __restrict__ qb8, const unsigned char* __restrict__ kvb,
    unsigned short* s1b,
    const int* __restrict__ offsets, const int* __restrict__ csr_src) {
  int w = threadIdx.x >> 6, l = threadIdx.x & 63;
  int g = l >> 4;            // edge slot 0..3
  int sub = l & 15;          // channel block (head = sub>>2)
  for (int n = blockIdx.x * 4 + w; n < N_NODES; n += gridDim.x * 4) {
    int i0 = offsets[n], i1 = offsets[n + 1];
    long ob = (long)n * 256 + sub * 16;
    if (i0 >= i1) {          // deg-0: h = relu(skip)
      if (g == 0) {
        u16x8 sv0 = *(const u16x8*)&s1b[ob];
        u16x8 sv1 = *(const u16x8*)&s1b[ob + 8];
        u16x8 h0, h1;
#pragma unroll
        for (int j = 0; j < 8; ++j) {
          h0[j] = (short)f2bf(fmaxf(bf2f((unsigned short)sv0[j]), 0.f));
          h1[j] = (short)f2bf(fmaxf(bf2f((unsigned short)sv1[j]), 0.f));
        }
        *(u16x8*)&s1b[ob] = h0;
        *(u16x8*)&s1b[ob + 8] = h1;
      }
      continue;
    }
    int4 qi = *(const int4*)&qb8[(long)n * 256 + sub * 16];
    float acc[16] = {};
    float se = 0.f;

    auto ldbatch = [&](int i, int4& ka, uint4& va, int4& kw, uint4& vw) {
      int ia = i + g, ib = i + 4 + g;
      int sa = csr_src[ia < i1 ? ia : i1 - 1];
      int sb = csr_src[ib < i1 ? ib : i1 - 1];
      const char* ba = (const char*)kvb + (long)sa * 512 + sub * 16;
      const char* bb = (const char*)kvb + (long)sb * 512 + sub * 16;
      ka = *(const int4*)ba; va = *(const uint4*)(ba + 256);
      kw = *(const int4*)bb; vw = *(const uint4*)(bb + 256);
    };
#define VACC(E, W, B) \
    acc[(B) + 0] = fmaf(E, (float)((W) & 0xffu), acc[(B) + 0]); \
    acc[(B) + 1] = fmaf(E, (float)(((W) >> 8) & 0xffu), acc[(B) + 1]); \
    acc[(B) + 2] = fmaf(E, (float)(((W) >> 16) & 0xffu), acc[(B) + 2]); \
    acc[(B) + 3] = fmaf(E, (float)((W) >> 24), acc[(B) + 3]);
    auto consume = [&](int i, int4 ka, uint4 va, int4 kw, uint4 vw) {
      int ia = i + g, ib = i + 4 + g;
      int da = 0, db = 0;
      da = dot4i8(qi.x, ka.x, da); da = dot4i8(qi.y, ka.y, da);
      da = dot4i8(qi.z, ka.z, da); da = dot4i8(qi.w, ka.w, da);
      db = dot4i8(qi.x, kw.x, db); db = dot4i8(qi.y, kw.y, db);
      db = dot4i8(qi.z, kw.z, db); db = dot4i8(qi.w, kw.w, db);
      da += __shfl_xor(da, 1); da += __shfl_xor(da, 2);
      db += __shfl_xor(db, 1); db += __shfl_xor(db, 2);
      float ea = (ia < i1) ? __expf((float)da * (1.f / 3072.f)) : 0.f;
      float eb = (ib < i1) ? __expf((float)db * (1.f / 3072.f)) : 0.f;
      se += ea + eb;
      VACC(ea, va.x, 0) VACC(ea, va.y, 4) VACC(ea, va.z, 8) VACC(ea, va.w, 12)
      VACC(eb, vw.x, 0) VACC(eb, vw.y, 4) VACC(eb, vw.z, 8) VACC(eb, vw.w, 12)
    };

    int i = i0;
    int4 ka0, kw0; uint4 va0, vw0;
    ldbatch(i, ka0, va0, kw0, vw0);
    for (; i + 8 < i1; i += 8) {
      int4 ka1, kw1; uint4 va1, vw1;
      ldbatch(i + 8, ka1, va1, kw1, vw1);     // prefetch next batch
      consume(i, ka0, va0, kw0, vw0);
      ka0 = ka1; va0 = va1; kw0 = kw1; vw0 = vw1;
    }
    consume(i, ka0, va0, kw0, vw0);
#undef VACC
#pragma unroll
    for (int j = 0; j < 16; ++j) {
      acc[j] += __shfl_xor(acc[j], 16);
      acc[j] += __shfl_xor(acc[j], 32);
    }
    se += __shfl_xor(se, 16);
    se += __shfl_xor(se, 32);
    if (g == 0) {
      float inv = (se > 0.f) ? 1.0f / se : 0.f;
      float bias = (se > 0.f) ? -8.0f : 0.f;
      u16x8 sv0 = *(const u16x8*)&s1b[ob];
      u16x8 sv1 = *(const u16x8*)&s1b[ob + 8];
      u16x8 h0, h1;
#pragma unroll
      for (int j = 0; j < 8; ++j) {
        float v0 = fmaf(acc[j] * inv, 0.0625f, bias);
        float v1 = fmaf(acc[8 + j] * inv, 0.0625f, bias);
        h0[j] = (short)f2bf(fmaxf(v0 + bf2f((unsigned short)sv0[j]), 0.f));
        h1[j] = (short)f2bf(fmaxf(v1 + bf2f((unsigned short)sv1[j]), 0.f));
      }
      *(u16x8*)&s1b[ob] = h0;
      *(u16x8*)&s1b[ob + 8] = h1;
    }
  }
}

// ---------------- layer-2 linear via MFMA: [NPAD x 256] @ [256 x 32] ----------------
__global__ __launch_bounds__(256) void lin2_kernel(const unsigned short* __restrict__ hb,
                                                   const unsigned short* __restrict__ w2bt,
                                                   const float* __restrict__ bias2,
                                                   float* __restrict__ qs2, float* __restrict__ kv2) {
  __shared__ unsigned short Bs2[32 * 264];
  __shared__ float bsh[32];
  for (int i = threadIdx.x; i < 32 * 32; i += 256) {
    int r = i >> 5, cc = i & 31;
    *(u16x8*)&Bs2[r * 264 + cc * 8] = *(const u16x8*)&w2bt[r * 256 + cc * 8];
  }
  if (threadIdx.x < 32) bsh[threadIdx.x] = (threadIdx.x < 20) ? bias2[threadIdx.x] : 0.f;
  __syncthreads();
  int w = threadIdx.x >> 6, l = threadIdx.x & 63;
  long row0 = (long)blockIdx.x * 128 + w * 32;
  int lr = l & 15, c0 = l >> 4;
  f32x4 acc[2][2] = {};
  for (int kk = 0; kk < 8; ++kk) {
    int koff = kk * 32 + c0 * 8;
    bf16x8 af[2], bfv[2];
    af[0] = *(const bf16x8*)&hb[(row0 + lr) * 256 + koff];
    af[1] = *(const bf16x8*)&hb[(row0 + 16 + lr) * 256 + koff];
    bfv[0] = *(const bf16x8*)&Bs2[lr * 264 + koff];
    bfv[1] = *(const bf16x8*)&Bs2[(16 + lr) * 264 + koff];
#pragma unroll
    for (int mf = 0; mf < 2; ++mf)
#pragma unroll
      for (int nf = 0; nf < 2; ++nf)
        acc[mf][nf] = __builtin_amdgcn_mfma_f32_16x16x32_bf16(af[mf], bfv[nf], acc[mf][nf], 0, 0, 0);
  }
#pragma unroll
  for (int mf = 0; mf < 2; ++mf) {
#pragma unroll
    for (int nf = 0; nf < 2; ++nf) {
      int col = nf * 16 + lr;
#pragma unroll
      for (int i = 0; i < 4; ++i) {
        long n = row0 + mf * 16 + c0 * 4 + i;
        float v = acc[mf][nf][i] + bsh[col];
        if (col < 5) qs2[n * 12 + col] = v;
        else if (col < 15) kv2[n * 12 + (col - 5)] = v;
        else if (col < 20) qs2[n * 12 + (col - 10)] = v;
      }
    }
  }
}

// ---------------- layer-2 fused attention (1 thread per node) ----------------
__global__ void agg2_kernel(const float* __restrict__ qs2, const float* __restrict__ kv2,
                            const int* __restrict__ offsets, const int* __restrict__ csr_src,
                            float* __restrict__ out) {
  int n = blockIdx.x * 256 + threadIdx.x;
  if (n >= N_NODES) return;
  const float* bn = &qs2[(long)n * 12];
  const float is5 = 0.4472135954999579f;  // 1/sqrt(5)
  float q[5], acc[5] = {0, 0, 0, 0, 0}, se = 0.f;
#pragma unroll
  for (int c = 0; c < 5; ++c) q[c] = bn[c] * is5;
  int i0 = offsets[n], i1 = offsets[n + 1];
  for (int i = i0; i < i1; ++i) {
    int s = csr_src[i];
    const float4* ps = (const float4*)&kv2[(long)s * 12];
    float4 A = ps[0], B = ps[1], C = ps[2];
    float lg = q[0] * A.x + q[1] * A.y + q[2] * A.z + q[3] * A.w + q[4] * B.x;
    float ee = __expf(lg);
    se += ee;
    acc[0] += ee * B.y; acc[1] += ee * B.z; acc[2] += ee * B.w;
    acc[3] += ee * C.x; acc[4] += ee * C.y;
  }
  float inv = 1.f / (se + 1e-16f);
#pragma unroll
  for (int c = 0; c < 5; ++c) out[(long)n * 5 + c] = acc[c] * inv + bn[5 + c];
}

// ---------------- launch ----------------
extern "C" void kernel_launch(void* const* d_in, const int* in_sizes, int n_in,
                              void* d_out, int out_size, void* d_ws, size_t ws_size,
                              hipStream_t stream) {
  (void)in_sizes; (void)n_in; (void)out_size; (void)ws_size;
  const float* x   = (const float*)d_in[0];
  const int* eidx  = (const int*)d_in[1];
  const int* esrc  = eidx;
  const int* edst  = eidx + N_EDGES;
  const float* Wq1 = (const float*)d_in[2];  const float* bq1 = (const float*)d_in[3];
  const float* Wk1 = (const float*)d_in[4];  const float* bk1 = (const float*)d_in[5];
  const float* Wv1 = (const float*)d_in[6];  const float* bv1 = (const float*)d_in[7];
  const float* Ws1 = (const float*)d_in[8];  const float* bs1 = (const float*)d_in[9];
  const float* Wq2 = (const float*)d_in[10]; const float* bq2 = (const float*)d_in[11];
  const float* Wk2 = (const float*)d_in[12]; const float* bk2 = (const float*)d_in[13];
  const float* Wv2 = (const float*)d_in[14]; const float* bv2 = (const float*)d_in[15];
  const float* Ws2 = (const float*)d_in[16]; const float* bs2 = (const float*)d_in[17];

  char* p = (char*)d_ws;
  auto take = [&](size_t bytes) { char* r = p; p += (bytes + 255) & ~(size_t)255; return r; };
  unsigned short* wbt = (unsigned short*)take((size_t)1024 * 384 * 2);
  float* bias1        = (float*)take(1024 * 4);
  char* qb8           = (char*)take((size_t)NPAD * 256);
  unsigned char* kvb  = (unsigned char*)take((size_t)NPAD * 512);
  unsigned short* s1b = (unsigned short*)take((size_t)NPAD * 256 * 2);
  unsigned short* w2bt = (unsigned short*)take(32 * 256 * 2);
  float* bias2        = (float*)take(32 * 4);
  float* qs2          = (float*)take((size_t)NPAD * 12 * 4);
  float* kv2          = (float*)take((size_t)NPAD * 12 * 4);
  int* counts         = (int*)take((size_t)N_NODES * 4);
  int* offsets        = (int*)take((size_t)(N_NODES + 1) * 4);
  int* cursor         = (int*)take((size_t)N_NODES * 4);
  int* csr_src        = (int*)take((size_t)N_EDGES * 4);
  int* scan_tmp       = (int*)take((size_t)N_NODES * 4);
  int* scan_bsum      = (int*)take(256 * 4);
  int* scan_bbase     = (int*)take(256 * 4);

  hipMemsetAsync(counts, 0, (size_t)N_NODES * 4, stream);
  prep_kernel<<<HIST_B + PW1_B + PW2_B, 256, 0, stream>>>(
      edst, counts, Wq1, Wk1, Wv1, Ws1, bq1, bk1, bv1, bs1, wbt, bias1,
      Wq2, Wk2, Wv2, Ws2, bq2, bk2, bv2, bs2, w2bt, bias2);
  scan1_kernel<<<SCAN_B, 256, 0, stream>>>(counts, scan_tmp, scan_bsum, N_NODES);
  scan2_kernel<<<1, 256, 0, stream>>>(scan_bsum, scan_bbase, SCAN_B);
  scan3_kernel<<<SCAN_B, 256, 0, stream>>>(scan_tmp, scan_bbase, offsets, cursor, N_NODES, N_EDGES);
  gemm_scatter_kernel<<<GEMM_B + SCAT_B, 512, 0, stream>>>(
      x, wbt, bias1, qb8, kvb, s1b, esrc, edst, cursor, csr_src);
  agg1_kernel<<<2048, 256, 0, stream>>>(qb8, kvb, s1b, offsets, csr_src);
  lin2_kernel<<<NPAD / 128, 256, 0, stream>>>(s1b, w2bt, bias2, qs2, kv2);
  agg2_kernel<<<(N_NODES + 255) / 256, 256, 0, stream>>>(qs2, kv2, offsets, csr_src, (float*)d_out);
}